// Round 2
// baseline (267.374 us; speedup 1.0000x reference)
//
#include <hip/hip_runtime.h>

// out[b, j, d] = exp(a[b, idx[j], d] * b[b, idx[j], d]
//                    + (a[b, idx[j], d] - b[b, idx[j], d]) * 0.5f) + 1.0f
// B=8, S=4096, D=1024, J=2048. Compute ONLY at gathered rows.
//
// Layout trick: launch exactly J=2048 blocks so blockIdx.x == j.
//  - idx[j] is loaded ONCE per block (was 8x across batch).
//  - The 8 batch iterations are independent -> compiler pipelines all
//    16 float4 loads (ILP), no dependent idx->row chain per iteration.
//  - 2048 blocks x 256 thr = 8192 waves: full occupancy, every CU busy.
//  - out is streaming/write-once: nontemporal stores keep the gathered
//    a/b rows (which have ~1.27x reuse from duplicate idx values) in L2.
//
// NOTE: __builtin_nontemporal_store requires a NATIVE vector type
// (clang ext_vector_type), not HIP's float4 class.

#define B_DIM 8
#define S_DIM 4096
#define D_DIM 1024
#define J_DIM 2048

typedef float vfloat4 __attribute__((ext_vector_type(4)));

__global__ __launch_bounds__(256) void tree_fused_gather_kernel(
    const float* __restrict__ a,
    const float* __restrict__ b,
    const int* __restrict__ idx,
    float* __restrict__ out)
{
    const int j   = blockIdx.x;          // 0 .. J_DIM-1
    const int s   = idx[j];              // block-uniform, loaded once
    const int d0  = threadIdx.x << 2;    // float4 lane offset within row

    const int src0 = s * D_DIM + d0;
    const int dst0 = j * D_DIM + d0;

    #pragma unroll
    for (int batch = 0; batch < B_DIM; ++batch) {
        const int src_off = batch * (S_DIM * D_DIM) + src0;
        const int dst_off = batch * (J_DIM * D_DIM) + dst0;

        const vfloat4 av = *reinterpret_cast<const vfloat4*>(a + src_off);
        const vfloat4 bv = *reinterpret_cast<const vfloat4*>(b + src_off);

        vfloat4 o;
        o.x = __expf(av.x * bv.x + (av.x - bv.x) * 0.5f) + 1.0f;
        o.y = __expf(av.y * bv.y + (av.y - bv.y) * 0.5f) + 1.0f;
        o.z = __expf(av.z * bv.z + (av.z - bv.z) * 0.5f) + 1.0f;
        o.w = __expf(av.w * bv.w + (av.w - bv.w) * 0.5f) + 1.0f;

        __builtin_nontemporal_store(o, reinterpret_cast<vfloat4*>(out + dst_off));
    }
}

extern "C" void kernel_launch(void* const* d_in, const int* in_sizes, int n_in,
                              void* d_out, int out_size, void* d_ws, size_t ws_size,
                              hipStream_t stream) {
    const float* a   = (const float*)d_in[0];
    const float* b   = (const float*)d_in[1];
    const int*   idx = (const int*)d_in[2];
    float* out = (float*)d_out;

    tree_fused_gather_kernel<<<J_DIM, 256, 0, stream>>>(a, b, idx, out);
}